// Round 2
// baseline (785.200 us; speedup 1.0000x reference)
//
#include <hip/hip_runtime.h>
#include <math.h>

#define B_      32
#define H_      2048
#define NH_     32
#define NKV_    8
#define HD_     64
#define G_      4        // NH/NKV
#define INTER_  8192
#define NBLK_   256
#define BS_     16
#define NCHUNK_ 8
#define CHUNK_  512

typedef float v2f __attribute__((ext_vector_type(2)));

// ---------------- ws layout (float offsets) ----------------
#define OFF_NORMED_T 0                    // [2048][32]
#define OFF_QKV_P    65536                // [16][32][3072]
#define OFF_QROPE    1638400              // [32][2048]
#define OFF_HT       1703936              // [2048][32]
#define OFF_ATTN_T   1769472              // [2048][32]
#define OFF_GU_P     1835008              // [8][32][16384]
#define OFF_ACT_T    6029312              // [8192][32]
#define OFF_O_P      6291456              // [16][32][2048]
#define OFF_D_P      7340032              // [32][32][2048]
#define OFF_OPART    9437184              // [8192][64]
#define OFF_MPART    9961472              // 8192
#define OFF_LPART    9969664              // 8192
// total 9977856 floats = ~40 MB

// ---------------- RMSNorm (x -> out_t transposed [H][B]) -------------------
__global__ __launch_bounds__(256) void rmsnorm_kernel(const float* __restrict__ xin,
                                                      const float* __restrict__ w,
                                                      float* __restrict__ out_t) {
    int b = blockIdx.x, tid = threadIdx.x;
    const float4* xr4 = (const float4*)(xin + (size_t)b * H_);
    float4 xv4[2];
    float ss = 0.f;
#pragma unroll
    for (int j = 0; j < 2; ++j) {
        float4 t = xr4[tid + j * 256];
        xv4[j] = t;
        ss += t.x * t.x + t.y * t.y + t.z * t.z + t.w * t.w;
    }
#pragma unroll
    for (int off = 32; off >= 1; off >>= 1) ss += __shfl_xor(ss, off, 64);
    __shared__ float red[4];
    __shared__ float rbc;
    if ((tid & 63) == 0) red[tid >> 6] = ss;
    __syncthreads();
    if (tid == 0) rbc = rsqrtf((red[0] + red[1] + red[2] + red[3]) / (float)H_ + 1e-5f);
    __syncthreads();
    float r = rbc;
#pragma unroll
    for (int j = 0; j < 2; ++j) {
        int col = (tid + j * 256) * 4;
        const float4 w4 = *(const float4*)&w[col];
        out_t[(size_t)(col + 0) * B_ + b] = xv4[j].x * r * w4.x;
        out_t[(size_t)(col + 1) * B_ + b] = xv4[j].y * r * w4.y;
        out_t[(size_t)(col + 2) * B_ + b] = xv4[j].z * r * w4.z;
        out_t[(size_t)(col + 3) * B_ + b] = xv4[j].w * r * w4.w;
    }
}

// ---------------- GEMV core: float4 weights, 4 cols x 32 batches ----------
// 256 threads: lane (tid&63) -> 4 consecutive cols; wave (tid>>6) -> k-split.
// Inner loop batch-paired on v2f so the backend emits v_pk_fma_f32 (2x fp32
// per instr). Per k-row/wave: 64 pk-fma + 16 dwordx2 x-loads vs 128 fma + 32.
__device__ __forceinline__ void gemv4_block(const float* __restrict__ xt,
                                            const float* __restrict__ W, int Nw,
                                            int wcol0, int rowsPerWave,
                                            float* __restrict__ part, int Nout,
                                            int outcol0) {
    int tid = threadIdx.x;
    int lane = tid & 63;
    int ks = tid >> 6;
    int k0 = (blockIdx.y * 4 + ks) * rowsPerWave;
    int wcol = wcol0 + lane * 4;

    v2f acc[4][16];   // acc[c][b2] = cols lane*4+c, batches {2*b2, 2*b2+1}
#pragma unroll
    for (int c = 0; c < 4; ++c)
#pragma unroll
        for (int b2 = 0; b2 < 16; ++b2) acc[c][b2] = (v2f)(0.f);

    const float* Wp = W + (size_t)k0 * Nw + wcol;
    const float* xp = xt + (size_t)k0 * B_;
#pragma unroll 2
    for (int k = 0; k < rowsPerWave; ++k) {
        float4 w4 = *(const float4*)(Wp + (size_t)k * Nw);
        v2f wa, wb, wc, wd;
        wa.x = w4.x; wa.y = w4.x;
        wb.x = w4.y; wb.y = w4.y;
        wc.x = w4.z; wc.y = w4.z;
        wd.x = w4.w; wd.y = w4.w;
        const float* xr = xp + k * B_;
#pragma unroll
        for (int b2 = 0; b2 < 16; ++b2) {
            v2f x2 = *(const v2f*)(xr + b2 * 2);
            acc[0][b2] = __builtin_elementwise_fma(wa, x2, acc[0][b2]);
            acc[1][b2] = __builtin_elementwise_fma(wb, x2, acc[1][b2]);
            acc[2][b2] = __builtin_elementwise_fma(wc, x2, acc[2][b2]);
            acc[3][b2] = __builtin_elementwise_fma(wd, x2, acc[3][b2]);
        }
    }

    __shared__ float red[4][2][260];
    float* prow = part + (size_t)blockIdx.y * B_ * Nout;
    // Force unroll: acc[] must be statically indexed or it spills to scratch
    // (runtime-indexed ext_vector arrays -> local memory, rule #20).
#pragma unroll
    for (int b0 = 0; b0 < B_; b0 += 2) {
#pragma unroll
        for (int bi = 0; bi < 2; ++bi)
#pragma unroll
            for (int c = 0; c < 4; ++c)
                red[ks][bi][lane * 4 + c] = acc[c][b0 >> 1][bi];
        __syncthreads();
#pragma unroll
        for (int bi = 0; bi < 2; ++bi) {
            float s = red[0][bi][tid] + red[1][bi][tid] + red[2][bi][tid] + red[3][bi][tid];
            prow[(size_t)(b0 + bi) * Nout + outcol0 + tid] = s;
        }
        __syncthreads();
    }
}

// qkv fused: grid(12,16).  q cols 0..2047, k 2048..2559, v 2560..3071
__global__ __launch_bounds__(256, 2) void gemv_qkv_kernel(const float* __restrict__ xt,
                                                          const float* __restrict__ qw,
                                                          const float* __restrict__ kw,
                                                          const float* __restrict__ vw,
                                                          float* __restrict__ part) {
    int cb = blockIdx.x;
    if (cb < 8)       gemv4_block(xt, qw, 2048, cb * 256, 32, part, 3072, cb * 256);
    else if (cb < 10) gemv4_block(xt, kw, 512, (cb - 8) * 256, 32, part, 3072, cb * 256);
    else              gemv4_block(xt, vw, 512, (cb - 10) * 256, 32, part, 3072, cb * 256);
}

// o-proj: grid(8,16)
__global__ __launch_bounds__(256, 2) void gemv_o_kernel(const float* __restrict__ xt,
                                                        const float* __restrict__ W,
                                                        float* __restrict__ part) {
    gemv4_block(xt, W, 2048, blockIdx.x * 256, 32, part, 2048, blockIdx.x * 256);
}

// gate+up: grid(64,8). gate cols 0..8191, up 8192..16383
__global__ __launch_bounds__(256, 2) void gemv_gateup_kernel(const float* __restrict__ xt,
                                                             const float* __restrict__ gw,
                                                             const float* __restrict__ uw,
                                                             float* __restrict__ part) {
    int cb = blockIdx.x;
    if (cb < 32) gemv4_block(xt, gw, 8192, cb * 256, 64, part, 16384, cb * 256);
    else         gemv4_block(xt, uw, 8192, (cb - 32) * 256, 64, part, 16384, 8192 + (cb - 32) * 256);
}

// down: grid(8,32)
__global__ __launch_bounds__(256, 2) void gemv_down_kernel(const float* __restrict__ xt,
                                                           const float* __restrict__ W,
                                                           float* __restrict__ part) {
    gemv4_block(xt, W, 2048, blockIdx.x * 256, 64, part, 2048, blockIdx.x * 256);
}

// ---------------- qkv partial reduce + RoPE + paged cache write ------------
__global__ __launch_bounds__(256) void qkv_reduce_rope_kernel(const float* __restrict__ part,
                                                              const int* __restrict__ btab,
                                                              const int* __restrict__ seql,
                                                              float* __restrict__ qrope,
                                                              float* __restrict__ kc,
                                                              float* __restrict__ vc) {
    int b = blockIdx.x, tid = threadIdx.x;
    __shared__ float s[3072];
#pragma unroll
    for (int j = 0; j < 3; ++j) {
        int col = (tid + j * 256) * 4;
        float4 a; a.x = 0.f; a.y = 0.f; a.z = 0.f; a.w = 0.f;
#pragma unroll
        for (int y = 0; y < 16; ++y) {
            const float4 p = *(const float4*)&part[((size_t)y * B_ + b) * 3072 + col];
            a.x += p.x; a.y += p.y; a.z += p.z; a.w += p.w;
        }
        *(float4*)&s[col] = a;
    }
    __syncthreads();
    int pos = seql[b];
    float fpos = (float)pos;
    const float LOG2T = 13.287712379549449f;  // log2(10000)
#pragma unroll
    for (int j = 0; j < 8; ++j) {
        int i = tid + j * 256;
        int d = i & 63, ii = d & 31;
        float ang = fpos * exp2f(-(float)(2 * ii) * (LOG2T / 64.f));
        float c = cosf(ang), sn = sinf(ang);
        float v1 = s[i], v2 = s[(d < 32) ? i + 32 : i - 32];
        qrope[(size_t)b * 2048 + i] = (d < 32) ? (v1 * c - v2 * sn) : (v1 * c + v2 * sn);
    }
    int blk = btab[b * NBLK_ + (pos >> 4)];
    size_t cbase = (size_t)(blk * BS_ + (pos & 15)) * NKV_ * HD_;
    for (int i = tid; i < NKV_ * HD_; i += 256) {
        int d = i & 63, ii = d & 31;
        float ang = fpos * exp2f(-(float)(2 * ii) * (LOG2T / 64.f));
        float c = cosf(ang), sn = sinf(ang);
        float v1 = s[2048 + i], v2 = s[2048 + ((d < 32) ? i + 32 : i - 32)];
        kc[cbase + i] = (d < 32) ? (v1 * c - v2 * sn) : (v1 * c + v2 * sn);
        vc[cbase + i] = s[2560 + i];
    }
}

// ---------------- flash-decode attention chunk (512 tokens) ---------------
// grid (NCHUNK, NKV, B), 256 threads
__global__ __launch_bounds__(256, 4) void attn_chunk_kernel(const float* __restrict__ qrope,
                                                            const float* __restrict__ kc,
                                                            const float* __restrict__ vc,
                                                            const int* __restrict__ btab,
                                                            const int* __restrict__ seqlens,
                                                            float* __restrict__ opart,
                                                            float* __restrict__ mpart,
                                                            float* __restrict__ lpart) {
    int cx = blockIdx.x, kv = blockIdx.y, b = blockIdx.z;
    int tid = threadIdx.x;
    int pos = seqlens[b];
    int c0 = cx * CHUNK_;
    int pidx = ((b * NKV_ + kv) * NCHUNK_ + cx) * G_;
    if (c0 > pos) {
        if (tid < G_) { mpart[pidx + tid] = -__builtin_inff(); lpart[pidx + tid] = 0.f; }
        return;
    }
    __shared__ float qlds[G_][HD_];
    __shared__ float slds[G_][CHUNK_];
    // V transposed: vtt[d][t_local]; stride 36 keeps 16B alignment for b128
    // float4 reads (36 % 4 == 0, tq multiple of 4).
    __shared__ float vtt[HD_][36];
    __shared__ int btl[32];
    if (tid < 32) btl[tid] = btab[b * NBLK_ + (c0 >> 4) + tid];
    {
        int h = tid >> 6, d = tid & 63;
        qlds[h][d] = qrope[((size_t)b * NH_ + kv * G_ + h) * HD_ + d] * 0.125f; // 1/sqrt(64)
    }
    __syncthreads();

    // pass 1: QK^T, 16 tokens x 16 threads (float4 each), coalesced
    int grp = tid >> 4, ln = tid & 15;
    for (int tb = 0; tb < CHUNK_; tb += 16) {
        int tl = tb + grp;
        int t = c0 + tl;
        int blk = btl[tl >> 4];
        const float4 k4 = *(const float4*)(kc + ((size_t)(blk * BS_ + (t & 15)) * NKV_ + kv) * HD_ + ln * 4);
        bool valid = (t <= pos);
#pragma unroll
        for (int h = 0; h < G_; ++h) {
            const float4 q4 = *(const float4*)&qlds[h][ln * 4];
            float p = q4.x * k4.x + q4.y * k4.y + q4.z * k4.z + q4.w * k4.w;
#pragma unroll
            for (int off = 8; off >= 1; off >>= 1) p += __shfl_xor(p, off, 16);
            if (ln == 0) slds[h][tl] = valid ? p : -__builtin_inff();
        }
    }
    __syncthreads();

    // softmax per head (wave h -> head h)
    int h = tid >> 6, lane = tid & 63;
    float m = -__builtin_inff();
    for (int i = lane; i < CHUNK_; i += 64) m = fmaxf(m, slds[h][i]);
#pragma unroll
    for (int off = 32; off >= 1; off >>= 1) m = fmaxf(m, __shfl_xor(m, off, 64));
    float l = 0.f;
    for (int i = lane; i < CHUNK_; i += 64) {
        float p = expf(slds[h][i] - m);
        slds[h][i] = p;
        l += p;
    }
#pragma unroll
    for (int off = 32; off >= 1; off >>= 1) l += __shfl_xor(l, off, 64);
    if (lane == 0) { mpart[pidx + h] = m; lpart[pidx + h] = l; }
    __syncthreads();

    // pass 2: P.V with V transposed in LDS; float4 reads on both operands.
    // Per 32-token tile per wave: 8 broadcast b128 (probs) + 8 lane b128 (V)
    // instead of 64 scalar ds_read_b32. 4 accumulators break the FMA chain.
    int d = lane;
    float oa0 = 0.f, oa1 = 0.f, oa2 = 0.f, oa3 = 0.f;
    int tmax = min(CHUNK_, pos + 1 - c0);
    for (int t0 = 0; t0 < tmax; t0 += 32) {
#pragma unroll
        for (int r = 0; r < 2; ++r) {
            int tl = t0 + r * 16 + (tid >> 4);
            int t = c0 + tl;
            int blk = btl[tl >> 4];
            // probs beyond tmax are exactly 0, so garbage V values are harmless
            // (v_cache is fully initialized -> finite).
            const float4 vv = *(const float4*)(vc + ((size_t)(blk * BS_ + (t & 15)) * NKV_ + kv) * HD_ + (tid & 15) * 4);
            int dd = (tid & 15) * 4, tc = r * 16 + (tid >> 4);
            vtt[dd + 0][tc] = vv.x;
            vtt[dd + 1][tc] = vv.y;
            vtt[dd + 2][tc] = vv.z;
            vtt[dd + 3][tc] = vv.w;
        }
        __syncthreads();
        {
            float4 p4, v4;
#define PV_STEP(tq, oacc) \
            p4 = *(const float4*)&slds[h][t0 + (tq)]; \
            v4 = *(const float4*)&vtt[d][(tq)]; \
            oacc = fmaf(p4.x, v4.x, oacc); oacc = fmaf(p4.y, v4.y, oacc); \
            oacc = fmaf(p4.z, v4.z, oacc); oacc = fmaf(p4.w, v4.w, oacc);
            PV_STEP(0,  oa0) PV_STEP(4,  oa1) PV_STEP(8,  oa2) PV_STEP(12, oa3)
            PV_STEP(16, oa0) PV_STEP(20, oa1) PV_STEP(24, oa2) PV_STEP(28, oa3)
#undef PV_STEP
        }
        __syncthreads();
    }
    float o = (oa0 + oa1) + (oa2 + oa3);
    opart[(size_t)(pidx + h) * HD_ + d] = o;
}

// ---------------- combine chunk partials ----------------------------------
__global__ __launch_bounds__(64) void attn_reduce_kernel(const float* __restrict__ opart,
                                                         const float* __restrict__ mpart,
                                                         const float* __restrict__ lpart,
                                                         float* __restrict__ attn_t) {
    int hq = blockIdx.x, b = blockIdx.y;
    int kv = hq >> 2, g = hq & 3;
    int lane = threadIdx.x;
    int base = ((b * NKV_ + kv) * NCHUNK_) * G_ + g;
    float mv[NCHUNK_], lv[NCHUNK_];
    float M = -__builtin_inff();
#pragma unroll
    for (int c = 0; c < NCHUNK_; ++c) {
        mv[c] = mpart[base + c * G_];
        lv[c] = lpart[base + c * G_];
        M = fmaxf(M, mv[c]);
    }
    float L = 0.f, o = 0.f;
#pragma unroll
    for (int c = 0; c < NCHUNK_; ++c) {
        if (lv[c] > 0.f) {
            float f = expf(mv[c] - M);
            L += lv[c] * f;
            o += f * opart[(size_t)(base + c * G_) * HD_ + lane];
        }
    }
    attn_t[(size_t)(hq * HD_ + lane) * B_ + b] = o / L;
}

// ---------------- o partial reduce + residual + RMSNorm2 + d_out copy ------
__global__ __launch_bounds__(256) void o_reduce_rms2_kernel(const float* __restrict__ part,
                                                            const float* __restrict__ x,
                                                            const float* __restrict__ w2,
                                                            float* __restrict__ out,
                                                            float* __restrict__ ht) {
    int b = blockIdx.x, tid = threadIdx.x;
    float4 v4[2];
    float ss = 0.f;
#pragma unroll
    for (int j = 0; j < 2; ++j) {
        int col = (tid + j * 256) * 4;
        float4 a = *(const float4*)&x[(size_t)b * H_ + col];
#pragma unroll
        for (int y = 0; y < 16; ++y) {
            const float4 p = *(const float4*)&part[((size_t)y * B_ + b) * 2048 + col];
            a.x += p.x; a.y += p.y; a.z += p.z; a.w += p.w;
        }
        v4[j] = a;
        ss += a.x * a.x + a.y * a.y + a.z * a.z + a.w * a.w;
    }
#pragma unroll
    for (int off = 32; off >= 1; off >>= 1) ss += __shfl_xor(ss, off, 64);
    __shared__ float red[4];
    __shared__ float rbc;
    if ((tid & 63) == 0) red[tid >> 6] = ss;
    __syncthreads();
    if (tid == 0) rbc = rsqrtf((red[0] + red[1] + red[2] + red[3]) / (float)H_ + 1e-5f);
    __syncthreads();
    float r = rbc;
#pragma unroll
    for (int j = 0; j < 2; ++j) {
        int col = (tid + j * 256) * 4;
        *(float4*)&out[(size_t)b * H_ + col] = v4[j];          // x2 residual into d_out
        const float4 w4 = *(const float4*)&w2[col];
        ht[(size_t)(col + 0) * B_ + b] = v4[j].x * r * w4.x;   // normed, transposed
        ht[(size_t)(col + 1) * B_ + b] = v4[j].y * r * w4.y;
        ht[(size_t)(col + 2) * B_ + b] = v4[j].z * r * w4.z;
        ht[(size_t)(col + 3) * B_ + b] = v4[j].w * r * w4.w;
    }
}

// ---------------- gate/up partial reduce + SiLU + transpose ----------------
__global__ __launch_bounds__(256) void gu_reduce_silu_kernel(const float* __restrict__ part,
                                                             float* __restrict__ act_t) {
    int j0 = blockIdx.x * 64, tid = threadIdx.x;
    int jj = tid & 63, bq = tid >> 6;
    __shared__ float tile[64][33];
#pragma unroll
    for (int bb = 0; bb < 8; ++bb) {
        int b = bq * 8 + bb;
        float g = 0.f, u = 0.f;
#pragma unroll
        for (int y = 0; y < 8; ++y) {
            size_t base = ((size_t)y * B_ + b) * 16384 + j0 + jj;
            g += part[base];
            u += part[base + 8192];
        }
        tile[jj][b] = (g / (1.f + expf(-g))) * u;
    }
    __syncthreads();
#pragma unroll
    for (int r = 0; r < 8; ++r) {
        int j = r * 8 + (tid >> 5);
        int bc = tid & 31;
        act_t[(size_t)(j0 + j) * B_ + bc] = tile[j][bc];
    }
}

// ---------------- down partial reduce + residual ---------------------------
__global__ __launch_bounds__(256) void down_reduce_kernel(const float* __restrict__ part,
                                                          float* __restrict__ out) {
    int idx = (blockIdx.x * 256 + threadIdx.x) * 4;   // 65536 outputs, float4
    float4 a = *(const float4*)&out[idx];             // x2 residual written earlier
#pragma unroll
    for (int y = 0; y < 32; ++y) {
        const float4 p = *(const float4*)&part[(size_t)y * 65536 + idx];
        a.x += p.x; a.y += p.y; a.z += p.z; a.w += p.w;
    }
    *(float4*)&out[idx] = a;
}

// ---------------------------------------------------------------------------
extern "C" void kernel_launch(void* const* d_in, const int* in_sizes, int n_in,
                              void* d_out, int out_size, void* d_ws, size_t ws_size,
                              hipStream_t stream) {
    const float* x       = (const float*)d_in[0];
    float*       k_cache = (float*)d_in[1];
    float*       v_cache = (float*)d_in[2];
    const float* ln1_w   = (const float*)d_in[3];
    const float* q_w     = (const float*)d_in[4];
    const float* k_w     = (const float*)d_in[5];
    const float* v_w     = (const float*)d_in[6];
    const float* o_w     = (const float*)d_in[7];
    const float* ln2_w   = (const float*)d_in[8];
    const float* gate_w  = (const float*)d_in[9];
    const float* up_w    = (const float*)d_in[10];
    const float* down_w  = (const float*)d_in[11];
    const int*   btab    = (const int*)d_in[12];
    const int*   seql    = (const int*)d_in[13];
    float* out = (float*)d_out;

    float* ws = (float*)d_ws;
    float* normed_t = ws + OFF_NORMED_T;
    float* qkv_p    = ws + OFF_QKV_P;
    float* qrope    = ws + OFF_QROPE;
    float* ht       = ws + OFF_HT;
    float* attn_t   = ws + OFF_ATTN_T;
    float* gu_p     = ws + OFF_GU_P;
    float* act_t    = ws + OFF_ACT_T;
    float* o_p      = ws + OFF_O_P;
    float* d_p      = ws + OFF_D_P;
    float* opart    = ws + OFF_OPART;
    float* mpart    = ws + OFF_MPART;
    float* lpart    = ws + OFF_LPART;

    rmsnorm_kernel<<<32, 256, 0, stream>>>(x, ln1_w, normed_t);
    gemv_qkv_kernel<<<dim3(12, 16), 256, 0, stream>>>(normed_t, q_w, k_w, v_w, qkv_p);
    qkv_reduce_rope_kernel<<<32, 256, 0, stream>>>(qkv_p, btab, seql, qrope, k_cache, v_cache);
    attn_chunk_kernel<<<dim3(NCHUNK_, NKV_, B_), 256, 0, stream>>>(qrope, k_cache, v_cache,
                                                                   btab, seql, opart, mpart, lpart);
    attn_reduce_kernel<<<dim3(NH_, B_), 64, 0, stream>>>(opart, mpart, lpart, attn_t);
    gemv_o_kernel<<<dim3(8, 16), 256, 0, stream>>>(attn_t, o_w, o_p);
    o_reduce_rms2_kernel<<<32, 256, 0, stream>>>(o_p, x, ln2_w, out, ht);
    gemv_gateup_kernel<<<dim3(64, 8), 256, 0, stream>>>(ht, gate_w, up_w, gu_p);
    gu_reduce_silu_kernel<<<128, 256, 0, stream>>>(gu_p, act_t);
    gemv_down_kernel<<<dim3(8, 32), 256, 0, stream>>>(act_t, down_w, d_p);
    down_reduce_kernel<<<64, 256, 0, stream>>>(d_p, out);
}